// Round 9
// baseline (248.964 us; speedup 1.0000x reference)
//
#include <hip/hip_runtime.h>
#include <math.h>

// Problem constants
#define NB    8
#define CIMG  64
#define HH    256
#define WW    256
#define NL    68
#define NP    136          // 2*NL
#define JD    128          // hidden dim
#define NSYS  71           // 68 + 3 rows
#define NCOL  73           // 71 matrix cols + 2 rhs
#define MPAD  75           // row stride in doubles: 150 dwords % 32 = 22, gcd 2 -> 2-way (free)
#define NCHK  32           // K1 split-K chunks
#define CHUNK4 1536        // float4 per chunk (6144 floats)
#define ROW4  49152        // float4 per K-row (196608/4)

// d_out (f32) layout: warped [0, 33554432), pred [33554432, +1088), norm at 33555520
#define OUT_PRED 33554432
#define OUT_NORM 33555520

// d_ws (float) layout
#define WS_PART 0          // 32*128*8 = 32768 floats
#define WS_NORM 32768      // 8 floats (per-batch sum of disp^2)
#define WS_DST  32784      // 8*136 floats (control points, y/x interleaved)
#define WS_WV   33920      // 8*142 floats (w[68][2] then v[3][2] per batch)

// ---------------------------------------------------------------- K1: h partials
__global__ __launch_bounds__(256) void k1_gemv(const float* __restrict__ x,
                                               const float* __restrict__ W1,
                                               float* __restrict__ part) {
  const int jg  = blockIdx.x;   // 0..31 : group of 4 output rows
  const int ch  = blockIdx.y;   // 0..31 : K chunk
  const int tid = threadIdx.x;
  const float4* __restrict__ xv = (const float4*)x;
  const float4* __restrict__ wv = (const float4*)W1;

  float acc[4][8];
#pragma unroll
  for (int a = 0; a < 4; ++a)
#pragma unroll
    for (int b = 0; b < 8; ++b) acc[a][b] = 0.f;

  const int base = ch * CHUNK4;
#pragma unroll
  for (int it = 0; it < 6; ++it) {
    const int k4 = base + it * 256 + tid;
    float4 w[4];
#pragma unroll
    for (int jj = 0; jj < 4; ++jj)
      w[jj] = wv[(size_t)(jg * 4 + jj) * ROW4 + k4];
#pragma unroll
    for (int b = 0; b < 8; ++b) {
      const float4 xr = xv[(size_t)b * ROW4 + k4];
#pragma unroll
      for (int jj = 0; jj < 4; ++jj) {
        acc[jj][b] = fmaf(w[jj].x, xr.x, acc[jj][b]);
        acc[jj][b] = fmaf(w[jj].y, xr.y, acc[jj][b]);
        acc[jj][b] = fmaf(w[jj].z, xr.z, acc[jj][b]);
        acc[jj][b] = fmaf(w[jj].w, xr.w, acc[jj][b]);
      }
    }
  }
  // wave64 reduction
#pragma unroll
  for (int jj = 0; jj < 4; ++jj)
#pragma unroll
    for (int b = 0; b < 8; ++b) {
      float v = acc[jj][b];
      for (int o = 32; o > 0; o >>= 1) v += __shfl_down(v, o, 64);
      acc[jj][b] = v;
    }
  __shared__ float sred[4][32];
  const int lane = tid & 63, wid = tid >> 6;
  if (lane == 0) {
#pragma unroll
    for (int jj = 0; jj < 4; ++jj)
#pragma unroll
      for (int b = 0; b < 8; ++b) sred[wid][jj * 8 + b] = acc[jj][b];
  }
  __syncthreads();
  if (tid < 32) {
    const float s = sred[0][tid] + sred[1][tid] + sred[2][tid] + sred[3][tid];
    const int jj = tid >> 3, b = tid & 7;
    part[((size_t)ch * JD + jg * 4 + jj) * 8 + b] = s;
  }
}

// augmented-system entry (f64), same numerics as rounds 2/4-8
__device__ __forceinline__ double sys_entry(int r, int c,
                                            const float* s_dst,
                                            const float* s_disp) {
  if (r < NL) {
    if (c < NL) {
      const double dy = (double)s_dst[2 * r]     - (double)s_dst[2 * c];
      const double dx = (double)s_dst[2 * r + 1] - (double)s_dst[2 * c + 1];
      const double d2 = dy * dy + dx * dx;
      double v = 0.5 * d2 * log(fmax(d2, 1e-10));
      if (r == c) v += 1e-6;
      return v;
    }
    if (c == 68) return (double)s_dst[2 * r];
    if (c == 69) return (double)s_dst[2 * r + 1];
    if (c == 70) return 1.0;
    return (double)s_disp[2 * r + (c - 71)];   // rhs cols 71,72
  }
  if (c < NL) {
    const int q = r - NL;
    return (q == 0) ? (double)s_dst[2 * c] : (q == 1) ? (double)s_dst[2 * c + 1] : 1.0;
  }
  return 0.0;
}

// ------------------- K2: landmarks + f64 TPS solve, matrix in LDS (row-major,
// pad 75 -> 2-way/free bank pattern). Lane = row (lane and lane+64); wave =
// interleaved column slice (c ≡ wv mod 4). Multipliers are per-lane registers;
// frozen rows never write, so pivot-row reads are stable broadcasts.
// 2 barriers per elimination step. Per-lane state: 2 bools + 2 ints — no
// register-allocator dependence (the r5-r8 designs all lost to scratch spill).
__global__ __launch_bounds__(256) void k2_land_solve(
    const float* __restrict__ part, const float* __restrict__ scales,
    const float* __restrict__ lmean, const float* __restrict__ b1,
    const float* __restrict__ W2, const float* __restrict__ b2,
    const float* __restrict__ W3, const float* __restrict__ b3,
    float* __restrict__ out, float* __restrict__ ws) {
  const int b = blockIdx.x, tid = threadIdx.x;
  const int lane = tid & 63, wv = tid >> 6;
  __shared__ float  s_h[JD];
  __shared__ float  s_dst[NP];
  __shared__ float  s_disp[NP];
  __shared__ double M[NSYS][MPAD];
  __shared__ int    s_perm[NSYS];
  __shared__ double s_inv;
  __shared__ int    s_pivv;

  // ---- h[b][j] = b1[j] + sum_chunks part
  if (tid < JD) {
    float s = b1[tid];
#pragma unroll 8
    for (int c = 0; c < NCHK; ++c) s += part[((size_t)c * JD + tid) * 8 + b];
    s_h[tid] = s;
  }
  __syncthreads();

  // ---- pred / disp
  const float scale_b = scales[b];
  if (tid < NP) {
    const float4* w2 = (const float4*)(W2 + (size_t)tid * JD);
    const float4* w3 = (const float4*)(W3 + (size_t)tid * JD);
    float a2 = 0.f, a3 = 0.f;
#pragma unroll 8
    for (int k = 0; k < 32; ++k) {
      const float4 u = w2[k], v = w3[k];
      const float h0 = s_h[4 * k], h1 = s_h[4 * k + 1];
      const float h2 = s_h[4 * k + 2], h3 = s_h[4 * k + 3];
      a2 = fmaf(u.x, h0, fmaf(u.y, h1, fmaf(u.z, h2, fmaf(u.w, h3, a2))));
      a3 = fmaf(v.x, h0, fmaf(v.y, h1, fmaf(v.z, h2, fmaf(v.w, h3, a3))));
    }
    const float pred = a2 + b2[tid] + lmean[tid];
    const float disp = (a3 + b3[tid]) * scale_b;
    out[OUT_PRED + b * NP + tid] = pred;
    s_dst[tid]  = pred + disp;
    s_disp[tid] = disp;
  }
  __syncthreads();

  // ---- norm partial + export control points
  if (tid < 64) {
    float s = 0.f;
    for (int i = tid; i < NP; i += 64) { const float d = s_disp[i]; s = fmaf(d, d, s); }
    for (int o = 32; o > 0; o >>= 1) s += __shfl_down(s, o, 64);
    if (tid == 0) ws[WS_NORM + b] = s;
  }
  if (tid < NP) ws[WS_DST + b * NP + tid] = s_dst[tid];

  // ---- build augmented system in LDS (row-major)
  for (int e = tid; e < NSYS * NCOL; e += 256) {
    const int r = e / NCOL, c = e - r * NCOL;
    M[r][c] = sys_entry(r, c, s_dst, s_disp);
  }
  __syncthreads();

  // ---- Gaussian elimination, no-swap partial pivoting, 2 barriers/step
  const int rowA = lane, rowB = lane + 64;
  const bool hasB = (rowB < NSYS);
  bool actA = true, actB = hasB;
  int slotA = 0, slotB = 0;

#pragma unroll 1
  for (int p = 0; p < NSYS; ++p) {
    if (wv == 0) {
      // packed argmax over active rows of |M[r][p]| (f32 prefix | row idx)
      unsigned ua = actA ? ((__float_as_uint((float)fabs(M[rowA][p])) & 0xFFFFFF80u) | (unsigned)rowA) : 0u;
      unsigned ub = (actB) ? ((__float_as_uint((float)fabs(M[rowB][p])) & 0xFFFFFF80u) | (unsigned)rowB) : 0u;
      unsigned u = ua > ub ? ua : ub;
#pragma unroll
      for (int o = 1; o < 64; o <<= 1) {
        const unsigned v = __shfl_xor(u, o);
        if (v > u) u = v;
      }
      const int piv = (int)(u & 0x7Fu);
      if (lane == 0) {
        s_pivv = piv;
        s_perm[p] = piv;
        s_inv = 1.0 / M[piv][p];
      }
    }
    __syncthreads();
    const int    piv = s_pivv;
    const double inv = s_inv;
    if (piv == rowA) { actA = false; slotA = p; }
    if (actB && piv == rowB) { actB = false; slotB = p; }
    const double mA = actA ? M[rowA][p] * inv : 0.0;
    const double mB = actB ? M[rowB][p] * inv : 0.0;

    // update owned columns c ≡ wv (mod 4), c > p. Pivot row is frozen (no
    // writes), so M[piv][c] reads are stable wave-broadcasts.
#pragma unroll 4
    for (int k = 0; k < 19; ++k) {
      const int c = wv + 4 * k;
      if (c > p && c < NCOL) {
        const double pvc = M[piv][c];
        if (actA) M[rowA][c] = fma(-mA, pvc, M[rowA][c]);
        if (actB) M[rowB][c] = fma(-mB, pvc, M[rowB][c]);
      }
    }
    __syncthreads();
  }

  // ---- back substitution (2 rhs) by wave 0; lane owns slots lane and lane+64
  if (wv == 0) {
    const int rpA = s_perm[lane];
    const int rpB = hasB ? s_perm[rowB] : 0;
    const double bb0a = M[rpA][NSYS], bb1a = M[rpA][NSYS + 1];
    const double diA = 1.0 / M[rpA][lane];
    double bb0b = 0.0, bb1b = 0.0, diB = 0.0;
    if (hasB) { bb0b = M[rpB][NSYS]; bb1b = M[rpB][NSYS + 1]; diB = 1.0 / M[rpB][rowB]; }
    double acc0a = 0.0, acc1a = 0.0, acc0b = 0.0, acc1b = 0.0;
    double sol0a = 0.0, sol1a = 0.0, sol0b = 0.0, sol1b = 0.0;
#pragma unroll 1
    for (int p = NSYS - 1; p >= 0; --p) {
      const double tA0 = (bb0a - acc0a) * diA;
      const double tA1 = (bb1a - acc1a) * diA;
      const double tB0 = (bb0b - acc0b) * diB;
      const double tB1 = (bb1b - acc1b) * diB;
      const bool fromB = (p >= 64);
      const int  src   = fromB ? (p - 64) : p;
      double x0 = fromB ? tB0 : tA0;
      double x1 = fromB ? tB1 : tA1;
      {
        const int lo0 = __builtin_amdgcn_readlane(__double2loint(x0), src);
        const int hi0 = __builtin_amdgcn_readlane(__double2hiint(x0), src);
        const int lo1 = __builtin_amdgcn_readlane(__double2loint(x1), src);
        const int hi1 = __builtin_amdgcn_readlane(__double2hiint(x1), src);
        x0 = __hiloint2double(hi0, lo0);
        x1 = __hiloint2double(hi1, lo1);
      }
      if (p >= 64) { if (lane == p - 64) { sol0b = tB0; sol1b = tB1; } }
      else         { if (lane == p)      { sol0a = tA0; sol1a = tA1; } }
      if (lane < p) {
        const double u2 = M[rpA][p];
        acc0a = fma(u2, x0, acc0a);
        acc1a = fma(u2, x1, acc1a);
      }
      if (hasB && rowB < p) {
        const double u2 = M[rpB][p];
        acc0b = fma(u2, x0, acc0b);
        acc1b = fma(u2, x1, acc1b);
      }
    }
    ws[WS_WV + (size_t)b * 142 + 2 * lane]     = (float)sol0a;
    ws[WS_WV + (size_t)b * 142 + 2 * lane + 1] = (float)sol1a;
    if (hasB) {
      ws[WS_WV + (size_t)b * 142 + 2 * rowB]     = (float)sol0b;
      ws[WS_WV + (size_t)b * 142 + 2 * rowB + 1] = (float)sol1b;
    }
  }
}

// ------------------------------- K3: fused spline eval + bilinear warp (+norm finalize)
__global__ __launch_bounds__(256) void k3_warp(const float* __restrict__ img,
                                               const float* __restrict__ ws,
                                               float* __restrict__ out) {
  const int orig = blockIdx.x;
  const int wgid = (orig & 7) * 256 + (orig >> 3);   // bijective (2048 % 8 == 0)
  const int b = wgid >> 8, y = wgid & 255;
  const int tid = threadIdx.x;   // = x

  if (orig == 0 && tid == 0) {
    float s = 0.f;
    for (int i = 0; i < NB; ++i) s += sqrtf(ws[WS_NORM + i]);
    out[OUT_NORM] = s * 0.125f;
  }

  __shared__ float s_c[NP], s_w[NP], s_v[6];
  if (tid < NP) {
    s_c[tid] = ws[WS_DST + b * NP + tid];
    s_w[tid] = ws[WS_WV + (size_t)b * 142 + tid];
  }
  if (tid >= NP && tid < NP + 6) s_v[tid - NP] = ws[WS_WV + (size_t)b * 142 + tid];
  __syncthreads();

  const float yf = (float)y, xf = (float)tid;
  float fy = fmaf(s_v[0], yf, fmaf(s_v[2], xf, s_v[4]));
  float fx = fmaf(s_v[1], yf, fmaf(s_v[3], xf, s_v[5]));
#pragma unroll 4
  for (int l = 0; l < NL; ++l) {
    const float dy = yf - s_c[2 * l];
    const float dx = xf - s_c[2 * l + 1];
    const float r  = fmaf(dy, dy, dx * dx);
    const float ph = 0.5f * r * __logf(fmaxf(r, 1e-10f));
    fy = fmaf(s_w[2 * l],     ph, fy);
    fx = fmaf(s_w[2 * l + 1], ph, fx);
  }

  const float qy = fminf(fmaxf(yf - fy, 0.f), 255.f);
  const float qx = fminf(fmaxf(xf - fx, 0.f), 255.f);
  int y0 = (int)floorf(qy); y0 = y0 > 254 ? 254 : y0;
  int x0 = (int)floorf(qx); x0 = x0 > 254 ? 254 : x0;
  const float wy = qy - (float)y0, wx = qx - (float)x0;
  const float w00 = (1.f - wy) * (1.f - wx), w01 = (1.f - wy) * wx;
  const float w10 = wy * (1.f - wx),         w11 = wy * wx;

  const float* p0 = img + (size_t)b * CIMG * 65536 + y0 * 256 + x0;
  const size_t ob = (size_t)b * CIMG * 65536 + (size_t)y * 256 + tid;
#pragma unroll 4
  for (int c = 0; c < CIMG; ++c) {
    const float* p = p0 + (size_t)c * 65536;
    const float v00 = p[0], v01 = p[1], v10 = p[256], v11 = p[257];
    const float val = fmaf(w00, v00, fmaf(w01, v01, fmaf(w10, v10, w11 * v11)));
    __builtin_nontemporal_store(val, &out[ob + (size_t)c * 65536]);
  }
}

// ------------------------------------------------------------------ launcher
extern "C" void kernel_launch(void* const* d_in, const int* in_sizes, int n_in,
                              void* d_out, int out_size, void* d_ws, size_t ws_size,
                              hipStream_t stream) {
  const float* x      = (const float*)d_in[0];
  const float* img    = (const float*)d_in[1];
  const float* scales = (const float*)d_in[2];
  const float* lmean  = (const float*)d_in[3];
  const float* W1     = (const float*)d_in[4];
  const float* b1     = (const float*)d_in[5];
  const float* W2     = (const float*)d_in[6];
  const float* b2     = (const float*)d_in[7];
  const float* W3     = (const float*)d_in[8];
  const float* b3     = (const float*)d_in[9];
  float* out = (float*)d_out;
  float* ws  = (float*)d_ws;

  k1_gemv<<<dim3(32, 32), 256, 0, stream>>>(x, W1, ws + WS_PART);
  k2_land_solve<<<NB, 256, 0, stream>>>(ws + WS_PART, scales, lmean, b1, W2, b2, W3, b3, out, ws);
  k3_warp<<<NB * HH, 256, 0, stream>>>(img, ws, out);
}